// Round 1
// baseline (213.523 us; speedup 1.0000x reference)
//
#include <hip/hip_runtime.h>
#include <math.h>

#define DIM 256
#define NSEG 8192

// One block per segment. batch is sorted, so segment g occupies a contiguous
// row range [start, end) found by binary search. 4 waves/block, each wave
// processes every 4th row; 64 lanes x float4 covers DIM=256.
__global__ __launch_bounds__(256) void readout_seg_kernel(
    const float* __restrict__ x,
    const int*   __restrict__ batch,
    const float* __restrict__ W,
    const float* __restrict__ bvec,
    float*       __restrict__ out,
    int n)
{
    const int g = blockIdx.x;

    // lower_bound(batch, g) -> start ; lower_bound(batch, g+1) -> end
    int lo = 0, hi = n;
    while (lo < hi) {
        int mid = (lo + hi) >> 1;
        if (batch[mid] < g) lo = mid + 1; else hi = mid;
    }
    const int start = lo;
    hi = n;
    while (lo < hi) {
        int mid = (lo + hi) >> 1;
        if (batch[mid] < g + 1) lo = mid + 1; else hi = mid;
    }
    const int end = lo;

    const int tid  = threadIdx.x;
    const int wave = tid >> 6;   // 0..3
    const int lane = tid & 63;   // 0..63

    // W fragment for this lane (dims lane*4 .. lane*4+3), cached in L1/L2.
    const float4 w4 = reinterpret_cast<const float4*>(W)[lane];
    const float bias = bvec[0];

    float4 acc_s = make_float4(0.f, 0.f, 0.f, 0.f);
    float4 acc_m = make_float4(-INFINITY, -INFINITY, -INFINITY, -INFINITY);

    for (int r = start + wave; r < end; r += 4) {
        const float4 xv =
            reinterpret_cast<const float4*>(x + (long long)r * DIM)[lane];

        // partial dot over this lane's 4 dims
        float dot = xv.x * w4.x + xv.y * w4.y + xv.z * w4.z + xv.w * w4.w;
        // 64-lane butterfly reduce (wave64)
        #pragma unroll
        for (int off = 32; off > 0; off >>= 1)
            dot += __shfl_xor(dot, off);

        const float score = 1.0f / (1.0f + expf(-(dot + bias)));

        acc_s.x = fmaf(score, xv.x, acc_s.x);
        acc_s.y = fmaf(score, xv.y, acc_s.y);
        acc_s.z = fmaf(score, xv.z, acc_s.z);
        acc_s.w = fmaf(score, xv.w, acc_s.w);

        acc_m.x = fmaxf(acc_m.x, xv.x);
        acc_m.y = fmaxf(acc_m.y, xv.y);
        acc_m.z = fmaxf(acc_m.z, xv.z);
        acc_m.w = fmaxf(acc_m.w, xv.w);
    }

    // combine the 4 waves' partials via LDS
    __shared__ float4 sm_s[4][64];
    __shared__ float4 sm_m[4][64];
    sm_s[wave][lane] = acc_s;
    sm_m[wave][lane] = acc_m;
    __syncthreads();

    if (wave == 0) {
        float4 S = sm_s[0][lane];
        float4 M = sm_m[0][lane];
        #pragma unroll
        for (int w2 = 1; w2 < 4; ++w2) {
            float4 s2 = sm_s[w2][lane];
            float4 m2 = sm_m[w2][lane];
            S.x += s2.x; S.y += s2.y; S.z += s2.z; S.w += s2.w;
            M.x = fmaxf(M.x, m2.x); M.y = fmaxf(M.y, m2.y);
            M.z = fmaxf(M.z, m2.z); M.w = fmaxf(M.w, m2.w);
        }
        // out row g: [0..255] = gated sum, [256..511] = raw max
        float* row = out + (long long)g * (2 * DIM);
        reinterpret_cast<float4*>(row)[lane]        = S;
        reinterpret_cast<float4*>(row + DIM)[lane]  = M;
    }
}

extern "C" void kernel_launch(void* const* d_in, const int* in_sizes, int n_in,
                              void* d_out, int out_size, void* d_ws, size_t ws_size,
                              hipStream_t stream) {
    const float* x     = (const float*)d_in[0];
    const int*   batch = (const int*)d_in[1];
    const float* W     = (const float*)d_in[2];
    const float* b     = (const float*)d_in[3];
    float* out = (float*)d_out;
    const int n = in_sizes[0] / DIM;  // 1,000,000 rows

    readout_seg_kernel<<<NSEG, 256, 0, stream>>>(x, batch, W, b, out, n);
}

// Round 2
// 201.820 us; speedup vs baseline: 1.0580x; 1.0580x over previous
//
#include <hip/hip_runtime.h>
#include <math.h>

#define DIM 256
#define NSEG 8192

// One block per segment (batch sorted -> contiguous row range via binary
// search). 4 waves/block; each wave takes a contiguous quarter of the range.
// 64 lanes x float4 = one full row per wave-load. Inner loop unrolled x4:
// 4 independent loads + 4 interleaved shfl-reduce chains for ILP/MLP.
__global__ __launch_bounds__(256) void readout_seg_kernel(
    const float* __restrict__ x,
    const int*   __restrict__ batch,
    const float* __restrict__ W,
    const float* __restrict__ bvec,
    float*       __restrict__ out,
    int n)
{
    const int g = blockIdx.x;

    // lower_bound(batch, g) and lower_bound(batch, g+1)
    int lo = 0, hi = n;
    while (lo < hi) {
        int mid = (lo + hi) >> 1;
        if (batch[mid] < g) lo = mid + 1; else hi = mid;
    }
    const int start = lo;
    hi = n;
    while (lo < hi) {
        int mid = (lo + hi) >> 1;
        if (batch[mid] < g + 1) lo = mid + 1; else hi = mid;
    }
    const int end = lo;
    const int len = end - start;

    const int tid  = threadIdx.x;
    const int wave = tid >> 6;
    const int lane = tid & 63;

    // this wave's contiguous sub-range
    const int wbeg = start + (int)(((long long)len * wave) >> 2);
    const int wend = start + (int)(((long long)len * (wave + 1)) >> 2);

    const float4 w4 = reinterpret_cast<const float4*>(W)[lane];
    const float bias = bvec[0];
    const float NLOG2E = -1.44269504088896f;

    float4 acc_s = make_float4(0.f, 0.f, 0.f, 0.f);
    float4 acc_m = make_float4(-INFINITY, -INFINITY, -INFINITY, -INFINITY);

    const float4* __restrict__ X4 = reinterpret_cast<const float4*>(x);

    int r = wbeg;
    for (; r + 3 < wend; r += 4) {
        const float4 v0 = X4[(long long)(r + 0) * 64 + lane];
        const float4 v1 = X4[(long long)(r + 1) * 64 + lane];
        const float4 v2 = X4[(long long)(r + 2) * 64 + lane];
        const float4 v3 = X4[(long long)(r + 3) * 64 + lane];

        float d0 = v0.x * w4.x + v0.y * w4.y + v0.z * w4.z + v0.w * w4.w;
        float d1 = v1.x * w4.x + v1.y * w4.y + v1.z * w4.z + v1.w * w4.w;
        float d2 = v2.x * w4.x + v2.y * w4.y + v2.z * w4.z + v2.w * w4.w;
        float d3 = v3.x * w4.x + v3.y * w4.y + v3.z * w4.z + v3.w * w4.w;

        #pragma unroll
        for (int off = 32; off > 0; off >>= 1) {
            d0 += __shfl_xor(d0, off);
            d1 += __shfl_xor(d1, off);
            d2 += __shfl_xor(d2, off);
            d3 += __shfl_xor(d3, off);
        }

        const float s0 = __builtin_amdgcn_rcpf(
            1.0f + __builtin_amdgcn_exp2f((d0 + bias) * NLOG2E));
        const float s1 = __builtin_amdgcn_rcpf(
            1.0f + __builtin_amdgcn_exp2f((d1 + bias) * NLOG2E));
        const float s2 = __builtin_amdgcn_rcpf(
            1.0f + __builtin_amdgcn_exp2f((d2 + bias) * NLOG2E));
        const float s3 = __builtin_amdgcn_rcpf(
            1.0f + __builtin_amdgcn_exp2f((d3 + bias) * NLOG2E));

        acc_s.x = fmaf(s0, v0.x, acc_s.x); acc_s.y = fmaf(s0, v0.y, acc_s.y);
        acc_s.z = fmaf(s0, v0.z, acc_s.z); acc_s.w = fmaf(s0, v0.w, acc_s.w);
        acc_s.x = fmaf(s1, v1.x, acc_s.x); acc_s.y = fmaf(s1, v1.y, acc_s.y);
        acc_s.z = fmaf(s1, v1.z, acc_s.z); acc_s.w = fmaf(s1, v1.w, acc_s.w);
        acc_s.x = fmaf(s2, v2.x, acc_s.x); acc_s.y = fmaf(s2, v2.y, acc_s.y);
        acc_s.z = fmaf(s2, v2.z, acc_s.z); acc_s.w = fmaf(s2, v2.w, acc_s.w);
        acc_s.x = fmaf(s3, v3.x, acc_s.x); acc_s.y = fmaf(s3, v3.y, acc_s.y);
        acc_s.z = fmaf(s3, v3.z, acc_s.z); acc_s.w = fmaf(s3, v3.w, acc_s.w);

        acc_m.x = fmaxf(acc_m.x, fmaxf(fmaxf(v0.x, v1.x), fmaxf(v2.x, v3.x)));
        acc_m.y = fmaxf(acc_m.y, fmaxf(fmaxf(v0.y, v1.y), fmaxf(v2.y, v3.y)));
        acc_m.z = fmaxf(acc_m.z, fmaxf(fmaxf(v0.z, v1.z), fmaxf(v2.z, v3.z)));
        acc_m.w = fmaxf(acc_m.w, fmaxf(fmaxf(v0.w, v1.w), fmaxf(v2.w, v3.w)));
    }

    for (; r < wend; ++r) {
        const float4 v = X4[(long long)r * 64 + lane];
        float d = v.x * w4.x + v.y * w4.y + v.z * w4.z + v.w * w4.w;
        #pragma unroll
        for (int off = 32; off > 0; off >>= 1) d += __shfl_xor(d, off);
        const float s = __builtin_amdgcn_rcpf(
            1.0f + __builtin_amdgcn_exp2f((d + bias) * NLOG2E));
        acc_s.x = fmaf(s, v.x, acc_s.x); acc_s.y = fmaf(s, v.y, acc_s.y);
        acc_s.z = fmaf(s, v.z, acc_s.z); acc_s.w = fmaf(s, v.w, acc_s.w);
        acc_m.x = fmaxf(acc_m.x, v.x);   acc_m.y = fmaxf(acc_m.y, v.y);
        acc_m.z = fmaxf(acc_m.z, v.z);   acc_m.w = fmaxf(acc_m.w, v.w);
    }

    // combine the 4 waves' partials via LDS
    __shared__ float4 sm_s[4][64];
    __shared__ float4 sm_m[4][64];
    sm_s[wave][lane] = acc_s;
    sm_m[wave][lane] = acc_m;
    __syncthreads();

    if (wave == 0) {
        float4 S = sm_s[0][lane];
        float4 M = sm_m[0][lane];
        #pragma unroll
        for (int w2 = 1; w2 < 4; ++w2) {
            float4 s2 = sm_s[w2][lane];
            float4 m2 = sm_m[w2][lane];
            S.x += s2.x; S.y += s2.y; S.z += s2.z; S.w += s2.w;
            M.x = fmaxf(M.x, m2.x); M.y = fmaxf(M.y, m2.y);
            M.z = fmaxf(M.z, m2.z); M.w = fmaxf(M.w, m2.w);
        }
        float* row = out + (long long)g * (2 * DIM);
        reinterpret_cast<float4*>(row)[lane]       = S;
        reinterpret_cast<float4*>(row + DIM)[lane] = M;
    }
}

extern "C" void kernel_launch(void* const* d_in, const int* in_sizes, int n_in,
                              void* d_out, int out_size, void* d_ws, size_t ws_size,
                              hipStream_t stream) {
    const float* x     = (const float*)d_in[0];
    const int*   batch = (const int*)d_in[1];
    const float* W     = (const float*)d_in[2];
    const float* b     = (const float*)d_in[3];
    float* out = (float*)d_out;
    const int n = in_sizes[0] / DIM;

    readout_seg_kernel<<<NSEG, 256, 0, stream>>>(x, batch, W, b, out, n);
}

// Round 4
// 194.780 us; speedup vs baseline: 1.0962x; 1.0361x over previous
//
#include <hip/hip_runtime.h>
#include <math.h>

#define DIM 256
#define NSEG 8192

// ---- DPP wave64 sum + broadcast (no LDS pipe) ----
// ctrl must be an immediate -> non-type template parameter.
template <int CTRL>
__device__ __forceinline__ float dpp_add(float v) {
    int t = __builtin_amdgcn_update_dpp(0, __float_as_int(v), CTRL, 0xf, 0xf, true);
    return v + __int_as_float(t);
}
__device__ __forceinline__ float wave64_sum_bcast(float v) {
    v = dpp_add<0x111>(v); // row_shr:1
    v = dpp_add<0x112>(v); // row_shr:2
    v = dpp_add<0x114>(v); // row_shr:4
    v = dpp_add<0x118>(v); // row_shr:8
    v = dpp_add<0x142>(v); // row_bcast:15
    v = dpp_add<0x143>(v); // row_bcast:31
    return __int_as_float(__builtin_amdgcn_readlane(__float_as_int(v), 63));
}

// ---- prologue: offs[g] = first row index with batch >= g ; offs[NSEG] = n ----
__global__ void seg_offsets_kernel(const int* __restrict__ batch, int n,
                                   int* __restrict__ offs) {
    int i = blockIdx.x * blockDim.x + threadIdx.x;
    if (i >= n) return;
    int b    = batch[i];
    int prev = (i == 0) ? -1 : batch[i - 1];
    for (int g = prev + 1; g <= b; ++g) offs[g] = i;
    if (i == n - 1)
        for (int g = b + 1; g <= NSEG; ++g) offs[g] = n;
}

// ---- main: one block per segment; 4 waves each take a contiguous quarter ----
__global__ __launch_bounds__(256) void readout_seg_kernel(
    const float* __restrict__ x,
    const int*   __restrict__ batch,
    const float* __restrict__ W,
    const float* __restrict__ bvec,
    const int*   __restrict__ offs,   // null -> binary-search fallback
    float*       __restrict__ out,
    int n)
{
    const int g = blockIdx.x;

    int start, end;
    if (offs) {
        start = offs[g];
        end   = offs[g + 1];
    } else {
        int lo = 0, hi = n;
        while (lo < hi) { int m = (lo + hi) >> 1; if (batch[m] < g) lo = m + 1; else hi = m; }
        start = lo; hi = n;
        while (lo < hi) { int m = (lo + hi) >> 1; if (batch[m] < g + 1) lo = m + 1; else hi = m; }
        end = lo;
    }
    const int len = end - start;

    const int tid  = threadIdx.x;
    const int wave = tid >> 6;
    const int lane = tid & 63;

    const int wbeg = start + (int)(((long long)len * wave) >> 2);
    const int wend = start + (int)(((long long)len * (wave + 1)) >> 2);

    const float4 w4  = reinterpret_cast<const float4*>(W)[lane];
    const float bias = bvec[0];
    const float NLOG2E = -1.44269504088896f;

    float4 acc_s = make_float4(0.f, 0.f, 0.f, 0.f);
    float4 acc_m = make_float4(-INFINITY, -INFINITY, -INFINITY, -INFINITY);

    const float4* __restrict__ X4 = reinterpret_cast<const float4*>(x);

    int r = wbeg;
    for (; r + 3 < wend; r += 4) {
        const float4 v0 = X4[(long long)(r + 0) * 64 + lane];
        const float4 v1 = X4[(long long)(r + 1) * 64 + lane];
        const float4 v2 = X4[(long long)(r + 2) * 64 + lane];
        const float4 v3 = X4[(long long)(r + 3) * 64 + lane];

        float d0 = v0.x * w4.x + v0.y * w4.y + v0.z * w4.z + v0.w * w4.w;
        float d1 = v1.x * w4.x + v1.y * w4.y + v1.z * w4.z + v1.w * w4.w;
        float d2 = v2.x * w4.x + v2.y * w4.y + v2.z * w4.z + v2.w * w4.w;
        float d3 = v3.x * w4.x + v3.y * w4.y + v3.z * w4.z + v3.w * w4.w;

        // 4 interleaved DPP reduce chains (VALU only, no DS ops)
        d0 = wave64_sum_bcast(d0);
        d1 = wave64_sum_bcast(d1);
        d2 = wave64_sum_bcast(d2);
        d3 = wave64_sum_bcast(d3);

        const float s0 = __builtin_amdgcn_rcpf(
            1.0f + __builtin_amdgcn_exp2f((d0 + bias) * NLOG2E));
        const float s1 = __builtin_amdgcn_rcpf(
            1.0f + __builtin_amdgcn_exp2f((d1 + bias) * NLOG2E));
        const float s2 = __builtin_amdgcn_rcpf(
            1.0f + __builtin_amdgcn_exp2f((d2 + bias) * NLOG2E));
        const float s3 = __builtin_amdgcn_rcpf(
            1.0f + __builtin_amdgcn_exp2f((d3 + bias) * NLOG2E));

        acc_s.x = fmaf(s0, v0.x, acc_s.x); acc_s.y = fmaf(s0, v0.y, acc_s.y);
        acc_s.z = fmaf(s0, v0.z, acc_s.z); acc_s.w = fmaf(s0, v0.w, acc_s.w);
        acc_s.x = fmaf(s1, v1.x, acc_s.x); acc_s.y = fmaf(s1, v1.y, acc_s.y);
        acc_s.z = fmaf(s1, v1.z, acc_s.z); acc_s.w = fmaf(s1, v1.w, acc_s.w);
        acc_s.x = fmaf(s2, v2.x, acc_s.x); acc_s.y = fmaf(s2, v2.y, acc_s.y);
        acc_s.z = fmaf(s2, v2.z, acc_s.z); acc_s.w = fmaf(s2, v2.w, acc_s.w);
        acc_s.x = fmaf(s3, v3.x, acc_s.x); acc_s.y = fmaf(s3, v3.y, acc_s.y);
        acc_s.z = fmaf(s3, v3.z, acc_s.z); acc_s.w = fmaf(s3, v3.w, acc_s.w);

        acc_m.x = fmaxf(acc_m.x, fmaxf(fmaxf(v0.x, v1.x), fmaxf(v2.x, v3.x)));
        acc_m.y = fmaxf(acc_m.y, fmaxf(fmaxf(v0.y, v1.y), fmaxf(v2.y, v3.y)));
        acc_m.z = fmaxf(acc_m.z, fmaxf(fmaxf(v0.z, v1.z), fmaxf(v2.z, v3.z)));
        acc_m.w = fmaxf(acc_m.w, fmaxf(fmaxf(v0.w, v1.w), fmaxf(v2.w, v3.w)));
    }

    for (; r < wend; ++r) {
        const float4 v = X4[(long long)r * 64 + lane];
        float d = v.x * w4.x + v.y * w4.y + v.z * w4.z + v.w * w4.w;
        d = wave64_sum_bcast(d);
        const float s = __builtin_amdgcn_rcpf(
            1.0f + __builtin_amdgcn_exp2f((d + bias) * NLOG2E));
        acc_s.x = fmaf(s, v.x, acc_s.x); acc_s.y = fmaf(s, v.y, acc_s.y);
        acc_s.z = fmaf(s, v.z, acc_s.z); acc_s.w = fmaf(s, v.w, acc_s.w);
        acc_m.x = fmaxf(acc_m.x, v.x);   acc_m.y = fmaxf(acc_m.y, v.y);
        acc_m.z = fmaxf(acc_m.z, v.z);   acc_m.w = fmaxf(acc_m.w, v.w);
    }

    __shared__ float4 sm_s[4][64];
    __shared__ float4 sm_m[4][64];
    sm_s[wave][lane] = acc_s;
    sm_m[wave][lane] = acc_m;
    __syncthreads();

    if (wave == 0) {
        float4 S = sm_s[0][lane];
        float4 M = sm_m[0][lane];
        #pragma unroll
        for (int w2 = 1; w2 < 4; ++w2) {
            float4 s2 = sm_s[w2][lane];
            float4 m2 = sm_m[w2][lane];
            S.x += s2.x; S.y += s2.y; S.z += s2.z; S.w += s2.w;
            M.x = fmaxf(M.x, m2.x); M.y = fmaxf(M.y, m2.y);
            M.z = fmaxf(M.z, m2.z); M.w = fmaxf(M.w, m2.w);
        }
        float* row = out + (long long)g * (2 * DIM);
        reinterpret_cast<float4*>(row)[lane]       = S;
        reinterpret_cast<float4*>(row + DIM)[lane] = M;
    }
}

extern "C" void kernel_launch(void* const* d_in, const int* in_sizes, int n_in,
                              void* d_out, int out_size, void* d_ws, size_t ws_size,
                              hipStream_t stream) {
    const float* x     = (const float*)d_in[0];
    const int*   batch = (const int*)d_in[1];
    const float* W     = (const float*)d_in[2];
    const float* b     = (const float*)d_in[3];
    float* out = (float*)d_out;
    const int n = in_sizes[0] / DIM;

    int* offs = nullptr;
    if (ws_size >= (size_t)(NSEG + 1) * sizeof(int)) {
        offs = (int*)d_ws;
        seg_offsets_kernel<<<(n + 255) / 256, 256, 0, stream>>>(batch, n, offs);
    }
    readout_seg_kernel<<<NSEG, 256, 0, stream>>>(x, batch, W, b, offs, out, n);
}

// Round 6
// 180.936 us; speedup vs baseline: 1.1801x; 1.0765x over previous
//
#include <hip/hip_runtime.h>
#include <math.h>

#define DIM 256
#define NSEG 8192

typedef float fx4 __attribute__((ext_vector_type(4)));

// ---- DPP wave64 sum + broadcast (VALU-only, no LDS pipe) ----
template <int CTRL>
__device__ __forceinline__ float dpp_add(float v) {
    int t = __builtin_amdgcn_update_dpp(0, __float_as_int(v), CTRL, 0xf, 0xf, true);
    return v + __int_as_float(t);
}
__device__ __forceinline__ float wave64_sum_bcast(float v) {
    v = dpp_add<0x111>(v); // row_shr:1
    v = dpp_add<0x112>(v); // row_shr:2
    v = dpp_add<0x114>(v); // row_shr:4
    v = dpp_add<0x118>(v); // row_shr:8
    v = dpp_add<0x142>(v); // row_bcast:15
    v = dpp_add<0x143>(v); // row_bcast:31
    return __int_as_float(__builtin_amdgcn_readlane(__float_as_int(v), 63));
}

// ---- prologue: offs[g] = first row with batch >= g ; offs[NSEG] = n ----
__global__ void seg_offsets_kernel(const int* __restrict__ batch, int n,
                                   int* __restrict__ offs) {
    int i = blockIdx.x * blockDim.x + threadIdx.x;
    if (i >= n) return;
    int b    = batch[i];
    int prev = (i == 0) ? -1 : batch[i - 1];
    for (int g = prev + 1; g <= b; ++g) offs[g] = i;
    if (i == n - 1)
        for (int g = b + 1; g <= NSEG; ++g) offs[g] = n;
}

// ---- main: one block per segment; waves ROW-INTERLEAVED (stride 4) so the
// block emits ONE near-sequential HBM stream instead of 4 disjoint ones. ----
__global__ __launch_bounds__(256) void readout_seg_kernel(
    const float* __restrict__ x,
    const float* __restrict__ W,
    const float* __restrict__ bvec,
    const int*   __restrict__ offs,
    float*       __restrict__ out)
{
    const int g = blockIdx.x;
    const int start = offs[g];
    const int end   = offs[g + 1];

    const int tid  = threadIdx.x;
    const int wave = tid >> 6;
    const int lane = tid & 63;

    const fx4 w4   = reinterpret_cast<const fx4*>(W)[lane];
    const float bias = bvec[0];
    const float NLOG2E = -1.44269504088896f;

    fx4 acc_s = (fx4){0.f, 0.f, 0.f, 0.f};
    fx4 acc_m = (fx4){-INFINITY, -INFINITY, -INFINITY, -INFINITY};

    const fx4* __restrict__ X4 = reinterpret_cast<const fx4*>(x);

    // wave w: rows start+w, start+w+4, ... ; unroll 2 (r and r+4) for MLP
    int r = start + wave;
    for (; r + 4 < end; r += 8) {
        const fx4 v0 = __builtin_nontemporal_load(&X4[(long long)r * 64 + lane]);
        const fx4 v1 = __builtin_nontemporal_load(&X4[(long long)(r + 4) * 64 + lane]);

        float d0 = v0.x * w4.x + v0.y * w4.y + v0.z * w4.z + v0.w * w4.w;
        float d1 = v1.x * w4.x + v1.y * w4.y + v1.z * w4.z + v1.w * w4.w;

        d0 = wave64_sum_bcast(d0);
        d1 = wave64_sum_bcast(d1);

        const float s0 = __builtin_amdgcn_rcpf(
            1.0f + __builtin_amdgcn_exp2f((d0 + bias) * NLOG2E));
        const float s1 = __builtin_amdgcn_rcpf(
            1.0f + __builtin_amdgcn_exp2f((d1 + bias) * NLOG2E));

        acc_s.x = fmaf(s0, v0.x, acc_s.x); acc_s.y = fmaf(s0, v0.y, acc_s.y);
        acc_s.z = fmaf(s0, v0.z, acc_s.z); acc_s.w = fmaf(s0, v0.w, acc_s.w);
        acc_s.x = fmaf(s1, v1.x, acc_s.x); acc_s.y = fmaf(s1, v1.y, acc_s.y);
        acc_s.z = fmaf(s1, v1.z, acc_s.z); acc_s.w = fmaf(s1, v1.w, acc_s.w);

        acc_m.x = fmaxf(acc_m.x, fmaxf(v0.x, v1.x));
        acc_m.y = fmaxf(acc_m.y, fmaxf(v0.y, v1.y));
        acc_m.z = fmaxf(acc_m.z, fmaxf(v0.z, v1.z));
        acc_m.w = fmaxf(acc_m.w, fmaxf(v0.w, v1.w));
    }

    if (r < end) {
        const fx4 v = __builtin_nontemporal_load(&X4[(long long)r * 64 + lane]);
        float d = v.x * w4.x + v.y * w4.y + v.z * w4.z + v.w * w4.w;
        d = wave64_sum_bcast(d);
        const float s = __builtin_amdgcn_rcpf(
            1.0f + __builtin_amdgcn_exp2f((d + bias) * NLOG2E));
        acc_s.x = fmaf(s, v.x, acc_s.x); acc_s.y = fmaf(s, v.y, acc_s.y);
        acc_s.z = fmaf(s, v.z, acc_s.z); acc_s.w = fmaf(s, v.w, acc_s.w);
        acc_m.x = fmaxf(acc_m.x, v.x);   acc_m.y = fmaxf(acc_m.y, v.y);
        acc_m.z = fmaxf(acc_m.z, v.z);   acc_m.w = fmaxf(acc_m.w, v.w);
    }

    __shared__ fx4 sm_s[4][64];
    __shared__ fx4 sm_m[4][64];
    sm_s[wave][lane] = acc_s;
    sm_m[wave][lane] = acc_m;
    __syncthreads();

    if (wave == 0) {
        fx4 S = sm_s[0][lane];
        fx4 M = sm_m[0][lane];
        #pragma unroll
        for (int w2 = 1; w2 < 4; ++w2) {
            fx4 s2 = sm_s[w2][lane];
            fx4 m2 = sm_m[w2][lane];
            S.x += s2.x; S.y += s2.y; S.z += s2.z; S.w += s2.w;
            M.x = fmaxf(M.x, m2.x); M.y = fmaxf(M.y, m2.y);
            M.z = fmaxf(M.z, m2.z); M.w = fmaxf(M.w, m2.w);
        }
        float* row = out + (long long)g * (2 * DIM);
        reinterpret_cast<fx4*>(row)[lane]       = S;
        reinterpret_cast<fx4*>(row + DIM)[lane] = M;
    }
}

extern "C" void kernel_launch(void* const* d_in, const int* in_sizes, int n_in,
                              void* d_out, int out_size, void* d_ws, size_t ws_size,
                              hipStream_t stream) {
    const float* x     = (const float*)d_in[0];
    const int*   batch = (const int*)d_in[1];
    const float* W     = (const float*)d_in[2];
    const float* b     = (const float*)d_in[3];
    float* out = (float*)d_out;
    const int n = in_sizes[0] / DIM;

    int* offs = (int*)d_ws;
    seg_offsets_kernel<<<(n + 255) / 256, 256, 0, stream>>>(batch, n, offs);
    readout_seg_kernel<<<NSEG, 256, 0, stream>>>(x, W, b, offs, out);
}

// Round 7
// 180.336 us; speedup vs baseline: 1.1840x; 1.0033x over previous
//
#include <hip/hip_runtime.h>
#include <math.h>

#define DIM 256
#define NSEG 8192

typedef float fx4 __attribute__((ext_vector_type(4)));

// ---- DPP wave64 sum + broadcast (VALU-only, no LDS pipe) ----
template <int CTRL>
__device__ __forceinline__ float dpp_add(float v) {
    int t = __builtin_amdgcn_update_dpp(0, __float_as_int(v), CTRL, 0xf, 0xf, true);
    return v + __int_as_float(t);
}
__device__ __forceinline__ float wave64_sum_bcast(float v) {
    v = dpp_add<0x111>(v); // row_shr:1
    v = dpp_add<0x112>(v); // row_shr:2
    v = dpp_add<0x114>(v); // row_shr:4
    v = dpp_add<0x118>(v); // row_shr:8
    v = dpp_add<0x142>(v); // row_bcast:15
    v = dpp_add<0x143>(v); // row_bcast:31
    return __int_as_float(__builtin_amdgcn_readlane(__float_as_int(v), 63));
}

__device__ __forceinline__ float fast_sigmoid(float d, float bias) {
    const float NLOG2E = -1.44269504088896f;
    return __builtin_amdgcn_rcpf(
        1.0f + __builtin_amdgcn_exp2f((d + bias) * NLOG2E));
}

// ---- prologue: offs[g] = first row with batch >= g ; offs[NSEG] = n ----
__global__ void seg_offsets_kernel(const int* __restrict__ batch, int n,
                                   int* __restrict__ offs) {
    int i = blockIdx.x * blockDim.x + threadIdx.x;
    if (i >= n) return;
    int b    = batch[i];
    int prev = (i == 0) ? -1 : batch[i - 1];
    for (int g = prev + 1; g <= b; ++g) offs[g] = i;
    if (i == n - 1)
        for (int g = b + 1; g <= NSEG; ++g) offs[g] = n;
}

// ---- main: one block per segment; waves row-interleaved (stride 4), each
// wave unrolled x4 (rows r, r+4, r+8, r+12) -> 4 KiB in flight per wave. ----
__global__ __launch_bounds__(256) void readout_seg_kernel(
    const float* __restrict__ x,
    const float* __restrict__ W,
    const float* __restrict__ bvec,
    const int*   __restrict__ offs,
    float*       __restrict__ out)
{
    const int g = blockIdx.x;
    const int start = offs[g];
    const int end   = offs[g + 1];

    const int tid  = threadIdx.x;
    const int wave = tid >> 6;
    const int lane = tid & 63;

    const fx4 w4   = reinterpret_cast<const fx4*>(W)[lane];
    const float bias = bvec[0];

    fx4 acc_s = (fx4){0.f, 0.f, 0.f, 0.f};
    fx4 acc_m = (fx4){-INFINITY, -INFINITY, -INFINITY, -INFINITY};

    const fx4* __restrict__ X4 = reinterpret_cast<const fx4*>(x);

    int r = start + wave;
    for (; r + 12 < end; r += 16) {
        const fx4 v0 = __builtin_nontemporal_load(&X4[(long long)(r     ) * 64 + lane]);
        const fx4 v1 = __builtin_nontemporal_load(&X4[(long long)(r +  4) * 64 + lane]);
        const fx4 v2 = __builtin_nontemporal_load(&X4[(long long)(r +  8) * 64 + lane]);
        const fx4 v3 = __builtin_nontemporal_load(&X4[(long long)(r + 12) * 64 + lane]);

        float d0 = v0.x * w4.x + v0.y * w4.y + v0.z * w4.z + v0.w * w4.w;
        float d1 = v1.x * w4.x + v1.y * w4.y + v1.z * w4.z + v1.w * w4.w;
        float d2 = v2.x * w4.x + v2.y * w4.y + v2.z * w4.z + v2.w * w4.w;
        float d3 = v3.x * w4.x + v3.y * w4.y + v3.z * w4.z + v3.w * w4.w;

        d0 = wave64_sum_bcast(d0);
        d1 = wave64_sum_bcast(d1);
        d2 = wave64_sum_bcast(d2);
        d3 = wave64_sum_bcast(d3);

        const float s0 = fast_sigmoid(d0, bias);
        const float s1 = fast_sigmoid(d1, bias);
        const float s2 = fast_sigmoid(d2, bias);
        const float s3 = fast_sigmoid(d3, bias);

        acc_s.x = fmaf(s0, v0.x, acc_s.x); acc_s.y = fmaf(s0, v0.y, acc_s.y);
        acc_s.z = fmaf(s0, v0.z, acc_s.z); acc_s.w = fmaf(s0, v0.w, acc_s.w);
        acc_s.x = fmaf(s1, v1.x, acc_s.x); acc_s.y = fmaf(s1, v1.y, acc_s.y);
        acc_s.z = fmaf(s1, v1.z, acc_s.z); acc_s.w = fmaf(s1, v1.w, acc_s.w);
        acc_s.x = fmaf(s2, v2.x, acc_s.x); acc_s.y = fmaf(s2, v2.y, acc_s.y);
        acc_s.z = fmaf(s2, v2.z, acc_s.z); acc_s.w = fmaf(s2, v2.w, acc_s.w);
        acc_s.x = fmaf(s3, v3.x, acc_s.x); acc_s.y = fmaf(s3, v3.y, acc_s.y);
        acc_s.z = fmaf(s3, v3.z, acc_s.z); acc_s.w = fmaf(s3, v3.w, acc_s.w);

        acc_m.x = fmaxf(acc_m.x, fmaxf(fmaxf(v0.x, v1.x), fmaxf(v2.x, v3.x)));
        acc_m.y = fmaxf(acc_m.y, fmaxf(fmaxf(v0.y, v1.y), fmaxf(v2.y, v3.y)));
        acc_m.z = fmaxf(acc_m.z, fmaxf(fmaxf(v0.z, v1.z), fmaxf(v2.z, v3.z)));
        acc_m.w = fmaxf(acc_m.w, fmaxf(fmaxf(v0.w, v1.w), fmaxf(v2.w, v3.w)));
    }

    for (; r < end; r += 4) {
        const fx4 v = __builtin_nontemporal_load(&X4[(long long)r * 64 + lane]);
        float d = v.x * w4.x + v.y * w4.y + v.z * w4.z + v.w * w4.w;
        d = wave64_sum_bcast(d);
        const float s = fast_sigmoid(d, bias);
        acc_s.x = fmaf(s, v.x, acc_s.x); acc_s.y = fmaf(s, v.y, acc_s.y);
        acc_s.z = fmaf(s, v.z, acc_s.z); acc_s.w = fmaf(s, v.w, acc_s.w);
        acc_m.x = fmaxf(acc_m.x, v.x);   acc_m.y = fmaxf(acc_m.y, v.y);
        acc_m.z = fmaxf(acc_m.z, v.z);   acc_m.w = fmaxf(acc_m.w, v.w);
    }

    __shared__ fx4 sm_s[4][64];
    __shared__ fx4 sm_m[4][64];
    sm_s[wave][lane] = acc_s;
    sm_m[wave][lane] = acc_m;
    __syncthreads();

    if (wave == 0) {
        fx4 S = sm_s[0][lane];
        fx4 M = sm_m[0][lane];
        #pragma unroll
        for (int w2 = 1; w2 < 4; ++w2) {
            fx4 s2 = sm_s[w2][lane];
            fx4 m2 = sm_m[w2][lane];
            S.x += s2.x; S.y += s2.y; S.z += s2.z; S.w += s2.w;
            M.x = fmaxf(M.x, m2.x); M.y = fmaxf(M.y, m2.y);
            M.z = fmaxf(M.z, m2.z); M.w = fmaxf(M.w, m2.w);
        }
        float* row = out + (long long)g * (2 * DIM);
        reinterpret_cast<fx4*>(row)[lane]       = S;
        reinterpret_cast<fx4*>(row + DIM)[lane] = M;
    }
}

extern "C" void kernel_launch(void* const* d_in, const int* in_sizes, int n_in,
                              void* d_out, int out_size, void* d_ws, size_t ws_size,
                              hipStream_t stream) {
    const float* x     = (const float*)d_in[0];
    const int*   batch = (const int*)d_in[1];
    const float* W     = (const float*)d_in[2];
    const float* b     = (const float*)d_in[3];
    float* out = (float*)d_out;
    const int n = in_sizes[0] / DIM;

    int* offs = (int*)d_ws;
    seg_offsets_kernel<<<(n + 255) / 256, 256, 0, stream>>>(batch, n, offs);
    readout_seg_kernel<<<NSEG, 256, 0, stream>>>(x, W, b, offs, out);
}